// Round 5
// baseline (315.787 us; speedup 1.0000x reference)
//
#include <hip/hip_runtime.h>

// Masked 3x3 conv as implicit GEMM over GATHERED pixels (mask==1 only).
//   C[f][p] = sum_{tap,c} Wt[f][tap*512+c] * Xt[(h_p+dh)*194+(w_p+dw)][c]
//   out = bias everywhere (prep_all), then out[f][pix(p)] = C[f][p]+bias[f].
// Round 5: double-buffered LDS (2x32KB), ONE barrier per K-iter. DMA for
// chunk k+1 is issued right after the barrier and drains at the NEXT
// barrier — a full iteration of in-flight distance (vs R4's half-iter,
// 2-barrier structure). Grid is block-starved (576 blocks, ~2.25/CU), so
// the 64KB LDS occupancy cap of 2 blocks/CU costs nothing.

typedef unsigned short ushort_t;
typedef __attribute__((ext_vector_type(8))) __bf16 bf16x8;
typedef __attribute__((ext_vector_type(4))) float f32x4;
typedef __attribute__((ext_vector_type(8))) unsigned short ushort8;

#define IMG_W 192
#define IMG_H 192
#define HW    36864       // 192*192
#define PAD_W 194
#define C_IN  512
#define F_OUT 512
#define KTOT  4608        // 9*512

__device__ __forceinline__ unsigned short f2bf(float f) {
  unsigned int u = __builtin_bit_cast(unsigned int, f);
  u += 0x7fffu + ((u >> 16) & 1u);
  return (unsigned short)(u >> 16);
}

__device__ __forceinline__ void async16(const void* g, void* l) {
  // 16B/lane global->LDS DMA; LDS dest is wave-uniform base + lane*16
  __builtin_amdgcn_global_load_lds(
      (const __attribute__((address_space(1))) unsigned int*)g,
      (__attribute__((address_space(3))) unsigned int*)l, 16, 0, 0);
}

// ============ prep_all: fused independent prep (1 dispatch) ============
// blocks [0,4608):      prep_x  (x NCHW fp32 -> padded NHWC bf16 interior)
// blocks [4608,5380):   halo_zero (772 border pixels of Xt)
// blocks [5380,6404):   prep_w  (w [f][c][3][3] -> Wt [f][tap*512+c])
// block  6404:          zero compaction counter
// blocks [6405,24837):  bias broadcast: out[f][*] = bias[f] (full lines)
__global__ void prep_all(const float* __restrict__ x, const float* __restrict__ w,
                         const float* __restrict__ bias,
                         ushort_t* __restrict__ Xt, ushort_t* __restrict__ Wt,
                         int* __restrict__ counter, float* __restrict__ out) {
  __shared__ float tile[64][65];
  const int bid = blockIdx.x;
  const int tid = threadIdx.x;

  if (bid < 4608) {
    // ---- prep_x ---- (64c x 64w LDS transpose)
    const int p  = bid;
    const int w0 = (p % 3) * 64;
    const int c0 = ((p / 3) & 7) * 64;
    const int h  = p / 24;

    const int wl_r = tid & 63;
    const int cg_r = tid >> 6;
    const float* src = x + (size_t)(c0 + cg_r * 16) * HW + (size_t)h * IMG_W + w0 + wl_r;
#pragma unroll
    for (int cc = 0; cc < 16; ++cc)
      tile[cg_r * 16 + cc][wl_r] = src[(size_t)cc * HW];
    __syncthreads();

    const int wl = tid >> 2;
    const int cg = tid & 3;
    ushort_t* dst = Xt + ((size_t)(h + 1) * PAD_W + (w0 + wl + 1)) * C_IN + c0 + cg * 16;
    ushort8 v0, v1;
#pragma unroll
    for (int cc = 0; cc < 8; ++cc) v0[cc] = f2bf(tile[cg * 16 + cc][wl]);
#pragma unroll
    for (int cc = 0; cc < 8; ++cc) v1[cc] = f2bf(tile[cg * 16 + 8 + cc][wl]);
    *(ushort8*)dst = v0;
    *(ushort8*)(dst + 8) = v1;
  } else if (bid < 5380) {
    // ---- halo_zero ----
    const int p = bid - 4608;
    int r, c;
    if (p < 388) { r = (p >= 194) ? 193 : 0; c = (p >= 194) ? p - 194 : p; }
    else         { int q = p - 388; r = 1 + (q >> 1); c = (q & 1) ? 193 : 0; }
    unsigned int* dst = (unsigned int*)(Xt + ((size_t)r * PAD_W + c) * C_IN);
    dst[tid] = 0;
  } else if (bid < 6404) {
    // ---- prep_w ----
    const int idx = (bid - 5380) * 256 + tid;   // f*512 + c
    const int f = idx >> 9;
    const int c = idx & 511;
    const float* src = w + (size_t)idx * 9;
    float v[9];
#pragma unroll
    for (int t = 0; t < 9; ++t) v[t] = src[t];
    ushort_t* dst = Wt + (size_t)f * KTOT + c;
#pragma unroll
    for (int t = 0; t < 9; ++t) dst[t * C_IN] = f2bf(v[t]);
  } else if (bid == 6404) {
    if (tid == 0) *counter = 0;
  } else {
    // ---- bias broadcast (float4 full lines) ----
    const int n4 = (bid - 6405) * 256 + tid;    // 18432*256 = 4.71M float4s
    const int f  = n4 / (HW / 4);
    const int r4 = n4 - f * (HW / 4);
    f32x4 bv = {bias[f], bias[f], bias[f], bias[f]};
    *(f32x4*)(out + (size_t)f * HW + (size_t)r4 * 4) = bv;
  }
}

// ---------------- compact: pixel ids where mask==1 (wave-aggregated) -------
__global__ void compact(const int* __restrict__ mask, int* __restrict__ list,
                        int* __restrict__ counter) {
  const int i = blockIdx.x * 256 + threadIdx.x;
  const int lane = threadIdx.x & 63;
  const int m = mask[i];
  unsigned long long b = __ballot(m != 0);
  int base = 0;
  if (lane == 0 && b) base = atomicAdd(counter, __popcll(b));
  base = __shfl(base, 0);
  if (m) list[base + __popcll(b & ((1ull << lane) - 1ull))] = i;
}

// ---------- implicit GEMM over gathered pixels, BK=64, LDS dbuf ----------
__global__ __launch_bounds__(256, 2) void conv_gemm(
    const ushort_t* __restrict__ Wt, const ushort_t* __restrict__ Xt,
    const float* __restrict__ bias, const int* __restrict__ list,
    const int* __restrict__ counter, float* __restrict__ out) {
  __shared__ __align__(16) ushort_t As[2][128 * 64];  // [buf][m][k], swizzled
  __shared__ __align__(16) ushort_t Bs[2][128 * 64];  // [buf][p][k], swizzled

  const int count = counter[0];
  const int n0 = blockIdx.x * 128;
  if (n0 >= count) return;

  const int tid  = threadIdx.x;
  const int lane = tid & 63;
  const int wave = tid >> 6;
  const int wm   = wave >> 1;
  const int wn   = wave & 1;
  const int m0   = blockIdx.y * 128;

  // ---- staging role: wave w stages rows [w*32, w*32+32) of A and B, via
  // 4 issues of 1KB (8 rows each). lane -> (row_rel = lane>>3, phys = lane&7).
  // Swizzle: phys slot p at row r holds logical chunk p ^ (r&7); here
  // r&7 == lane>>3, so each lane's logical chunk q is loop-invariant.
  const int rrel = lane >> 3;
  const int q    = (lane & 7) ^ rrel;

  const ushort_t* aSrc = Wt + (size_t)(m0 + wave * 32 + rrel) * KTOT + q * 8;

  unsigned int bOffs[4];
#pragma unroll
  for (int ii = 0; ii < 4; ++ii) {
    const int pos = n0 + wave * 32 + ii * 8 + rrel;
    const int pix = (pos < count) ? list[pos] : 0;
    const int hh = pix / IMG_W, ww = pix - hh * IMG_W;
    bOffs[ii] = ((hh + 1) * PAD_W + (ww + 1)) * C_IN + q * 8;
  }

  const int wofs = wave * 32 * 64;   // wave's 32-row slab (2048 elems)

  const int col  = lane & 15;
  const int quad = lane >> 4;

  f32x4 acc[4][4] = {};

  // initial staging: chunk 0 (tap 0, kc 0) into buf 0
  {
    const int toff0 = -(PAD_W + 1) * C_IN;
#pragma unroll
    for (int ii = 0; ii < 4; ++ii) {
      async16(aSrc + (size_t)ii * 8 * KTOT, &As[0][wofs + ii * 512]);
      async16(Xt + (int)bOffs[ii] + toff0, &Bs[0][wofs + ii * 512]);
    }
  }

#pragma unroll 1
  for (int kk = 0; kk < 72; ++kk) {
    __syncthreads();   // per-wave vmcnt drain: DMA for chunk kk (issued one
                       // full iteration ago) is complete; buf[kk&1] ready.
    // issue DMA for chunk kk+1 into the OTHER buffer (in flight all iter)
    if (kk < 71) {
      const int kn    = kk + 1;
      const int tapn  = kn >> 3;
      const int kcn   = (kn & 7) * 64;
      const int toffn = ((tapn / 3) * PAD_W + (tapn % 3) - (PAD_W + 1)) * C_IN;
      const int aoffn = tapn * 512 + kcn;
      ushort_t* aD = &As[kn & 1][wofs];
      ushort_t* bD = &Bs[kn & 1][wofs];
#pragma unroll
      for (int ii = 0; ii < 4; ++ii) {
        async16(aSrc + (size_t)ii * 8 * KTOT + aoffn, aD + ii * 512);
        async16(Xt + (int)bOffs[ii] + toffn + kcn, bD + ii * 512);
      }
    }

    const ushort_t* Ab = As[kk & 1];
    const ushort_t* Bb = Bs[kk & 1];
    bf16x8 af[2][4], bfr[2][4];
#pragma unroll
    for (int s = 0; s < 2; ++s) {
#pragma unroll
      for (int i = 0; i < 4; ++i) {
        const int row = wm * 64 + i * 16 + col;
        af[s][i] = *(const bf16x8*)&Ab[row * 64 + ((s * 4 + quad) ^ (row & 7)) * 8];
      }
#pragma unroll
      for (int j = 0; j < 4; ++j) {
        const int row = wn * 64 + j * 16 + col;
        bfr[s][j] = *(const bf16x8*)&Bb[row * 64 + ((s * 4 + quad) ^ (row & 7)) * 8];
      }
    }
#pragma unroll
    for (int s = 0; s < 2; ++s)
#pragma unroll
      for (int i = 0; i < 4; ++i)
#pragma unroll
        for (int j = 0; j < 4; ++j)
          acc[i][j] = __builtin_amdgcn_mfma_f32_16x16x32_bf16(af[s][i], bfr[s][j],
                                                              acc[i][j], 0, 0, 0);
  }

  // epilogue: out[mrow][pix] = acc + bias   (C/D: col=lane&15, row=quad*4+r)
#pragma unroll
  for (int j = 0; j < 4; ++j) {
    const int pos = n0 + wn * 64 + j * 16 + col;
    if (pos < count) {
      const int n_pix = list[pos];
#pragma unroll
      for (int i = 0; i < 4; ++i) {
        const int mrow = m0 + wm * 64 + i * 16 + quad * 4;
        float* o = out + (size_t)mrow * HW + n_pix;
#pragma unroll
        for (int r = 0; r < 4; ++r)
          o[(size_t)r * HW] = acc[i][j][r] + bias[mrow + r];
      }
    }
  }
}

extern "C" void kernel_launch(void* const* d_in, const int* in_sizes, int n_in,
                              void* d_out, int out_size, void* d_ws, size_t ws_size,
                              hipStream_t stream) {
  const float* x    = (const float*)d_in[0];  // [512][192][192]
  const float* w    = (const float*)d_in[1];  // [512][512][3][3]
  const float* bias = (const float*)d_in[2];  // [512]
  const int*   mask = (const int*)d_in[3];    // [192][192]
  float* out = (float*)d_out;                 // [512][192][192]

  // ws layout: list (36864 int) | counter | pad | Xt (38.5MB) | Wt (4.7MB)
  int* list    = (int*)d_ws;
  int* counter = list + HW;
  ushort_t* Xt = (ushort_t*)((char*)d_ws + 147712);   // 16B-aligned
  ushort_t* Wt = Xt + (size_t)PAD_W * PAD_W * C_IN;

  prep_all<<<dim3(24837), 256, 0, stream>>>(x, w, bias, Xt, Wt, counter, out);
  compact<<<dim3(HW / 256), 256, 0, stream>>>(mask, list, counter);
  conv_gemm<<<dim3((HW + 127) / 128, F_OUT / 128), 256, 0, stream>>>(
      Wt, Xt, bias, list, counter, out);
}

// Round 6
// 266.578 us; speedup vs baseline: 1.1846x; 1.1846x over previous
//
#include <hip/hip_runtime.h>

// Masked 3x3 conv as implicit GEMM over GATHERED pixels (mask==1 only).
//   C[f][p] = sum_{tap,c} Wt[f][tap*512+c] * Xt[(h_p+dh)*194+(w_p+dw)][c]
//   out = bias everywhere (prep_all), then out[f][pix(p)] = C[f][p]+bias[f].
// Round 6: revert to R4's 2-barrier BK=64 single-buffer conv (115 us; R5's
// dbuf lost occupancy and regressed) + XCD co-residency swizzle: the 4
// m-blocks sharing one B panel launch adjacently on one XCD (d&7), so the
// panel is fetched once into that XCD's L2 and hit by the other three.

typedef unsigned short ushort_t;
typedef __attribute__((ext_vector_type(8))) __bf16 bf16x8;
typedef __attribute__((ext_vector_type(4))) float f32x4;
typedef __attribute__((ext_vector_type(8))) unsigned short ushort8;

#define IMG_W 192
#define IMG_H 192
#define HW    36864       // 192*192
#define PAD_W 194
#define C_IN  512
#define F_OUT 512
#define KTOT  4608        // 9*512

__device__ __forceinline__ unsigned short f2bf(float f) {
  unsigned int u = __builtin_bit_cast(unsigned int, f);
  u += 0x7fffu + ((u >> 16) & 1u);
  return (unsigned short)(u >> 16);
}

__device__ __forceinline__ void async16(const void* g, void* l) {
  // 16B/lane global->LDS DMA; LDS dest is wave-uniform base + lane*16
  __builtin_amdgcn_global_load_lds(
      (const __attribute__((address_space(1))) unsigned int*)g,
      (__attribute__((address_space(3))) unsigned int*)l, 16, 0, 0);
}

// ============ prep_all: fused independent prep (1 dispatch) ============
// blocks [0,4608):      prep_x  (x NCHW fp32 -> padded NHWC bf16 interior)
// blocks [4608,5380):   halo_zero (772 border pixels of Xt)
// blocks [5380,6404):   prep_w  (w [f][c][3][3] -> Wt [f][tap*512+c])
// block  6404:          zero compaction counter
// blocks [6405,24837):  bias broadcast: out[f][*] = bias[f] (full lines)
__global__ void prep_all(const float* __restrict__ x, const float* __restrict__ w,
                         const float* __restrict__ bias,
                         ushort_t* __restrict__ Xt, ushort_t* __restrict__ Wt,
                         int* __restrict__ counter, float* __restrict__ out) {
  __shared__ float tile[64][65];
  const int bid = blockIdx.x;
  const int tid = threadIdx.x;

  if (bid < 4608) {
    // ---- prep_x ---- (64c x 64w LDS transpose)
    const int p  = bid;
    const int w0 = (p % 3) * 64;
    const int c0 = ((p / 3) & 7) * 64;
    const int h  = p / 24;

    const int wl_r = tid & 63;
    const int cg_r = tid >> 6;
    const float* src = x + (size_t)(c0 + cg_r * 16) * HW + (size_t)h * IMG_W + w0 + wl_r;
#pragma unroll
    for (int cc = 0; cc < 16; ++cc)
      tile[cg_r * 16 + cc][wl_r] = src[(size_t)cc * HW];
    __syncthreads();

    const int wl = tid >> 2;
    const int cg = tid & 3;
    ushort_t* dst = Xt + ((size_t)(h + 1) * PAD_W + (w0 + wl + 1)) * C_IN + c0 + cg * 16;
    ushort8 v0, v1;
#pragma unroll
    for (int cc = 0; cc < 8; ++cc) v0[cc] = f2bf(tile[cg * 16 + cc][wl]);
#pragma unroll
    for (int cc = 0; cc < 8; ++cc) v1[cc] = f2bf(tile[cg * 16 + 8 + cc][wl]);
    *(ushort8*)dst = v0;
    *(ushort8*)(dst + 8) = v1;
  } else if (bid < 5380) {
    // ---- halo_zero ----
    const int p = bid - 4608;
    int r, c;
    if (p < 388) { r = (p >= 194) ? 193 : 0; c = (p >= 194) ? p - 194 : p; }
    else         { int q = p - 388; r = 1 + (q >> 1); c = (q & 1) ? 193 : 0; }
    unsigned int* dst = (unsigned int*)(Xt + ((size_t)r * PAD_W + c) * C_IN);
    dst[tid] = 0;
  } else if (bid < 6404) {
    // ---- prep_w ----
    const int idx = (bid - 5380) * 256 + tid;   // f*512 + c
    const int f = idx >> 9;
    const int c = idx & 511;
    const float* src = w + (size_t)idx * 9;
    float v[9];
#pragma unroll
    for (int t = 0; t < 9; ++t) v[t] = src[t];
    ushort_t* dst = Wt + (size_t)f * KTOT + c;
#pragma unroll
    for (int t = 0; t < 9; ++t) dst[t * C_IN] = f2bf(v[t]);
  } else if (bid == 6404) {
    if (tid == 0) *counter = 0;
  } else {
    // ---- bias broadcast (float4 full lines) ----
    const int n4 = (bid - 6405) * 256 + tid;    // 18432*256 = 4.71M float4s
    const int f  = n4 / (HW / 4);
    const int r4 = n4 - f * (HW / 4);
    f32x4 bv = {bias[f], bias[f], bias[f], bias[f]};
    *(f32x4*)(out + (size_t)f * HW + (size_t)r4 * 4) = bv;
  }
}

// ---------------- compact: pixel ids where mask==1 (wave-aggregated) -------
__global__ void compact(const int* __restrict__ mask, int* __restrict__ list,
                        int* __restrict__ counter) {
  const int i = blockIdx.x * 256 + threadIdx.x;
  const int lane = threadIdx.x & 63;
  const int m = mask[i];
  unsigned long long b = __ballot(m != 0);
  int base = 0;
  if (lane == 0 && b) base = atomicAdd(counter, __popcll(b));
  base = __shfl(base, 0);
  if (m) list[base + __popcll(b & ((1ull << lane) - 1ull))] = i;
}

// ---------------- implicit GEMM over gathered pixels, BK=64 ----------------
__global__ __launch_bounds__(256, 3) void conv_gemm(
    const ushort_t* __restrict__ Wt, const ushort_t* __restrict__ Xt,
    const float* __restrict__ bias, const int* __restrict__ list,
    const int* __restrict__ counter, float* __restrict__ out) {
  __shared__ __align__(16) ushort_t As[128 * 64];  // [m 0..127][k 0..63], swizzled
  __shared__ __align__(16) ushort_t Bs[128 * 64];  // [p 0..127][k 0..63], swizzled

  const int count = counter[0];

  // ---- XCD co-residency swizzle: d&7 = XCD (dispatch round-robin), the 4
  // m-blocks of one n-panel get consecutive d on ONE XCD -> B panel L2 reuse.
  const int d     = blockIdx.y * 288 + blockIdx.x;   // 0..1151
  const int n_blk = (d & 7) + 8 * (d >> 5);          // 0..287
  const int m_blk = (d >> 3) & 3;                    // 0..3
  const int n0 = n_blk * 128;
  if (n0 >= count) return;
  const int m0 = m_blk * 128;

  const int tid  = threadIdx.x;
  const int lane = tid & 63;
  const int wave = tid >> 6;
  const int wm   = wave >> 1;
  const int wn   = wave & 1;

  // ---- staging role: wave w stages rows [w*32, w*32+32) of A and B, via
  // 4 issues of 1KB (8 rows each). lane -> (row_rel = lane>>3, phys = lane&7).
  // Swizzle: phys slot p at row r holds logical chunk p ^ (r&7); here
  // r&7 == lane>>3, so each lane's logical chunk q is loop-invariant.
  const int rrel = lane >> 3;
  const int q    = (lane & 7) ^ rrel;

  const ushort_t* aSrc = Wt + (size_t)(m0 + wave * 32 + rrel) * KTOT + q * 8;

  unsigned int bOffs[4];
#pragma unroll
  for (int ii = 0; ii < 4; ++ii) {
    const int pos = n0 + wave * 32 + ii * 8 + rrel;
    const int pix = (pos < count) ? list[pos] : 0;
    const int hh = pix / IMG_W, ww = pix - hh * IMG_W;
    bOffs[ii] = ((hh + 1) * PAD_W + (ww + 1)) * C_IN + q * 8;
  }

  ushort_t* aDst = &As[wave * 32 * 64];  // + ii*512 per issue (8 rows x 64)
  ushort_t* bDst = &Bs[wave * 32 * 64];

  const int col  = lane & 15;
  const int quad = lane >> 4;

  f32x4 acc[4][4] = {};

  // initial staging (kk=0: tap 0, kc 0)
  {
    const int toff0 = -(PAD_W + 1) * C_IN;
#pragma unroll
    for (int ii = 0; ii < 4; ++ii) {
      async16(aSrc + (size_t)ii * 8 * KTOT, aDst + ii * 512);
      async16(Xt + (int)bOffs[ii] + toff0, bDst + ii * 512);
    }
  }

#pragma unroll 1
  for (int kk = 0; kk < 72; ++kk) {
    __syncthreads();   // staging for kk ready (drains vmcnt; DMA was in
                       // flight during the previous chunk's MFMA burst)
    bf16x8 af[2][4], bfr[2][4];
#pragma unroll
    for (int s = 0; s < 2; ++s) {
#pragma unroll
      for (int i = 0; i < 4; ++i) {
        const int row = wm * 64 + i * 16 + col;
        af[s][i] = *(const bf16x8*)&As[row * 64 + ((s * 4 + quad) ^ (row & 7)) * 8];
      }
#pragma unroll
      for (int j = 0; j < 4; ++j) {
        const int row = wn * 64 + j * 16 + col;
        bfr[s][j] = *(const bf16x8*)&Bs[row * 64 + ((s * 4 + quad) ^ (row & 7)) * 8];
      }
    }
    if (kk < 71) {
      __syncthreads();   // all waves done reading LDS; safe to overwrite
      const int kn   = kk + 1;
      const int tapn = kn >> 3;
      const int kcn  = (kn & 7) * 64;
      const int toffn = ((tapn / 3) * PAD_W + (tapn % 3) - (PAD_W + 1)) * C_IN;
      const int aoffn = tapn * 512 + kcn;
#pragma unroll
      for (int ii = 0; ii < 4; ++ii) {
        async16(aSrc + (size_t)ii * 8 * KTOT + aoffn, aDst + ii * 512);
        async16(Xt + (int)bOffs[ii] + toffn + kcn, bDst + ii * 512);
      }
    }
#pragma unroll
    for (int s = 0; s < 2; ++s)
#pragma unroll
      for (int i = 0; i < 4; ++i)
#pragma unroll
        for (int j = 0; j < 4; ++j)
          acc[i][j] = __builtin_amdgcn_mfma_f32_16x16x32_bf16(af[s][i], bfr[s][j],
                                                              acc[i][j], 0, 0, 0);
  }

  // epilogue: out[mrow][pix] = acc + bias   (C/D: col=lane&15, row=quad*4+r)
#pragma unroll
  for (int j = 0; j < 4; ++j) {
    const int pos = n0 + wn * 64 + j * 16 + col;
    if (pos < count) {
      const int n_pix = list[pos];
#pragma unroll
      for (int i = 0; i < 4; ++i) {
        const int mrow = m0 + wm * 64 + i * 16 + quad * 4;
        float* o = out + (size_t)mrow * HW + n_pix;
#pragma unroll
        for (int r = 0; r < 4; ++r)
          o[(size_t)r * HW] = acc[i][j][r] + bias[mrow + r];
      }
    }
  }
}

extern "C" void kernel_launch(void* const* d_in, const int* in_sizes, int n_in,
                              void* d_out, int out_size, void* d_ws, size_t ws_size,
                              hipStream_t stream) {
  const float* x    = (const float*)d_in[0];  // [512][192][192]
  const float* w    = (const float*)d_in[1];  // [512][512][3][3]
  const float* bias = (const float*)d_in[2];  // [512]
  const int*   mask = (const int*)d_in[3];    // [192][192]
  float* out = (float*)d_out;                 // [512][192][192]

  // ws layout: list (36864 int) | counter | pad | Xt (38.5MB) | Wt (4.7MB)
  int* list    = (int*)d_ws;
  int* counter = list + HW;
  ushort_t* Xt = (ushort_t*)((char*)d_ws + 147712);   // 16B-aligned
  ushort_t* Wt = Xt + (size_t)PAD_W * PAD_W * C_IN;

  prep_all<<<dim3(24837), 256, 0, stream>>>(x, w, bias, Xt, Wt, counter, out);
  compact<<<dim3(HW / 256), 256, 0, stream>>>(mask, list, counter);
  conv_gemm<<<dim3((HW + 127) / 128, F_OUT / 128), 256, 0, stream>>>(
      Wt, Xt, bias, list, counter, out);
}